// Round 5
// baseline (708.988 us; speedup 1.0000x reference)
//
#include <hip/hip_runtime.h>
#include <math.h>

#define NN 100000
#define NE 1600000
#define ATTN_SLOPE 0.2f
#define ACT_SLOPE 0.01f

#define NBUK 512
#define BK 196            // 512*196 = 100352 >= NN; dst/BK <= 510
#define CAP 5120          // LDS staging capacity per bucket (mean 3125, 8s tail)

typedef __attribute__((ext_vector_type(8))) short bf16x8;
typedef __attribute__((ext_vector_type(4))) float f32x4;

__global__ void zero_ints(int* __restrict__ a, int n) {
    int i = blockIdx.x * blockDim.x + threadIdx.x;
    if (i < n) a[i] = 0;
}

// ---- phase 0: per-bucket edge counts (LDS-aggregated histogram) ----
__global__ void __launch_bounds__(256) bucket_hist(const int* __restrict__ dst,
                                                   int* __restrict__ bcount, int E) {
    __shared__ int h[NBUK];
    for (int i = threadIdx.x; i < NBUK; i += 256) h[i] = 0;
    __syncthreads();
    for (int i = blockIdx.x * 256 + threadIdx.x; i < E; i += gridDim.x * 256)
        atomicAdd(&h[dst[i] / BK], 1);
    __syncthreads();
    for (int i = threadIdx.x; i < NBUK; i += 256)
        if (h[i]) atomicAdd(&bcount[i], h[i]);
}

// ---- phase 1: exclusive scan of 512 bucket counts ----
__global__ void __launch_bounds__(NBUK) scan512(const int* __restrict__ bcount,
                                                int* __restrict__ bbase, int* __restrict__ offs) {
    __shared__ int lds[NBUK];
    const int t = threadIdx.x;
    const int v = bcount[t];
    lds[t] = v;
    __syncthreads();
    for (int off = 1; off < NBUK; off <<= 1) {
        int u = (t >= off) ? lds[t - off] : 0;
        __syncthreads();
        lds[t] += u;
        __syncthreads();
    }
    bbase[t] = lds[t] - v;
    if (t == NBUK - 1) { bbase[NBUK] = lds[t]; offs[NN] = lds[t]; }
}

// ---- phase 2: scatter edges into bucket-major tmp (4B packed, tail-clustered writes) ----
__global__ void __launch_bounds__(256) bucket_scatter(const int* __restrict__ src,
                                                      const int* __restrict__ dst,
                                                      const int* __restrict__ bbase,
                                                      int* __restrict__ btail,
                                                      int* __restrict__ tmp, int E) {
    for (int i = blockIdx.x * 256 + threadIdx.x; i < E; i += gridDim.x * 256) {
        const int d = dst[i];
        const int b = d / BK;
        const int dloc = d - b * BK;
        const int pos = bbase[b] + atomicAdd(&btail[b], 1);
        tmp[pos] = (src[i] << 8) | dloc;
    }
}

// ---- phase 3: one block per bucket -> local hist+scan in LDS, emit offs + csr ----
__global__ void __launch_bounds__(256) bucket_build(const int* __restrict__ tmp,
                                                    const int* __restrict__ bbase,
                                                    int* __restrict__ offs,
                                                    int* __restrict__ csr_src) {
    __shared__ int epack[CAP];
    __shared__ int csr_loc[CAP];
    __shared__ int cnt[256];
    __shared__ int loff[256];
    const int b = blockIdx.x;
    const int t = threadIdx.x;
    const int ebeg = bbase[b];
    const int nE = bbase[b + 1] - ebeg;
    const int nlo = b * BK;
    const int nn = (nlo < NN) ? ((NN - nlo < BK) ? (NN - nlo) : BK) : 0;
    const bool fits = (nE <= CAP);

    cnt[t] = 0;
    __syncthreads();
    for (int i = t; i < nE; i += 256) {
        const int p = tmp[ebeg + i];
        if (fits) epack[i] = p;
        atomicAdd(&cnt[p & 255], 1);
    }
    __syncthreads();
    // in-place Hillis-Steele inclusive scan over 256 counters
    const int v = cnt[t];
    for (int off = 1; off < 256; off <<= 1) {
        int u = (t >= off) ? cnt[t - off] : 0;
        __syncthreads();
        cnt[t] += u;
        __syncthreads();
    }
    const int excl = cnt[t] - v;
    loff[t] = excl;
    __syncthreads();
    cnt[t] = 0;                       // reuse as per-node tails
    if (t < nn) offs[nlo + t] = ebeg + excl;
    __syncthreads();
    for (int i = t; i < nE; i += 256) {
        const int p = fits ? epack[i] : tmp[ebeg + i];
        const int dloc = p & 255;
        const int pos = loff[dloc] + atomicAdd(&cnt[dloc], 1);
        if (fits) csr_loc[pos] = p >> 8;
        else csr_src[ebeg + pos] = p >> 8;
    }
    __syncthreads();
    if (fits)
        for (int i = t; i < nE; i += 256) csr_src[ebeg + i] = csr_loc[i];
}

// round-to-nearest-even fp32 -> bf16 bits
__device__ __forceinline__ unsigned short bfr(float f) {
    unsigned int u = __builtin_bit_cast(unsigned int, f);
    return (unsigned short)((u + 0x7fffu + ((u >> 16) & 1u)) >> 16);
}
__device__ __forceinline__ float bf2f(unsigned short h) {
    return __builtin_bit_cast(float, ((unsigned int)h) << 16);
}

// feat = x @ W via bf16x3-split MFMA (error ~2^-16, fp32-equivalent).
template <int DIN>
__global__ void __launch_bounds__(256) gemm_mfma_kernel(
        const float* __restrict__ x, const float* __restrict__ W,
        const float* __restrict__ al, const float* __restrict__ ar,
        float* __restrict__ feat, float* __restrict__ el, float* __restrict__ er,
        int nPairTiles) {
    constexpr int KS = DIN / 32;
    const int lane = threadIdx.x & 63;
    const int tw = threadIdx.x >> 6;
    const int colhalf = tw & 1;
    const int l15 = lane & 15;
    const int g = lane >> 4;
    const int colbase = colhalf * 32;

    bf16x8 Bhi[KS][2], Blo[KS][2];
#pragma unroll
    for (int ks = 0; ks < KS; ++ks) {
#pragma unroll
        for (int ct = 0; ct < 2; ++ct) {
            const int col = colbase + ct * 16 + l15;
#pragma unroll
            for (int j = 0; j < 8; ++j) {
                float w = W[(ks * 32 + g * 8 + j) * 64 + col];
                unsigned short h = bfr(w);
                Bhi[ks][ct][j] = (short)h;
                Blo[ks][ct][j] = (short)bfr(w - bf2f(h));
            }
        }
    }
    const float alc0 = al[colbase + l15];
    const float arc0 = ar[colbase + l15];
    const float alc1 = al[colbase + 16 + l15];
    const float arc1 = ar[colbase + 16 + l15];

#pragma unroll 1
    for (int pt = blockIdx.x; pt < nPairTiles; pt += gridDim.x) {
        const int rb = pt * 32 + (tw >> 1) * 16;
        f32x4 acc0 = {0.f, 0.f, 0.f, 0.f};
        f32x4 acc1 = {0.f, 0.f, 0.f, 0.f};
#pragma unroll
        for (int ks = 0; ks < KS; ++ks) {
            const float* xp = x + (size_t)(rb + l15) * DIN + ks * 32 + g * 8;
            f32x4 xa = *(const f32x4*)xp;
            f32x4 xb = *(const f32x4*)(xp + 4);
            bf16x8 Ahi, Alo;
#pragma unroll
            for (int j = 0; j < 4; ++j) {
                unsigned short h = bfr(xa[j]);
                Ahi[j] = (short)h;
                Alo[j] = (short)bfr(xa[j] - bf2f(h));
            }
#pragma unroll
            for (int j = 0; j < 4; ++j) {
                unsigned short h = bfr(xb[j]);
                Ahi[4 + j] = (short)h;
                Alo[4 + j] = (short)bfr(xb[j] - bf2f(h));
            }
            acc0 = __builtin_amdgcn_mfma_f32_16x16x32_bf16(Ahi, Bhi[ks][0], acc0, 0, 0, 0);
            acc0 = __builtin_amdgcn_mfma_f32_16x16x32_bf16(Ahi, Blo[ks][0], acc0, 0, 0, 0);
            acc0 = __builtin_amdgcn_mfma_f32_16x16x32_bf16(Alo, Bhi[ks][0], acc0, 0, 0, 0);
            acc1 = __builtin_amdgcn_mfma_f32_16x16x32_bf16(Ahi, Bhi[ks][1], acc1, 0, 0, 0);
            acc1 = __builtin_amdgcn_mfma_f32_16x16x32_bf16(Ahi, Blo[ks][1], acc1, 0, 0, 0);
            acc1 = __builtin_amdgcn_mfma_f32_16x16x32_bf16(Alo, Bhi[ks][1], acc1, 0, 0, 0);
        }
#pragma unroll
        for (int i = 0; i < 4; ++i) {
            const int n = rb + g * 4 + i;
            feat[(size_t)n * 64 + colbase + l15] = acc0[i];
            feat[(size_t)n * 64 + colbase + 16 + l15] = acc1[i];
            float vl0 = acc0[i] * alc0, vr0 = acc0[i] * arc0;
            float vl1 = acc1[i] * alc1, vr1 = acc1[i] * arc1;
#pragma unroll
            for (int d = 1; d < 8; d <<= 1) {
                vl0 += __shfl_xor(vl0, d); vr0 += __shfl_xor(vr0, d);
                vl1 += __shfl_xor(vl1, d); vr1 += __shfl_xor(vr1, d);
            }
            if ((lane & 7) == 0) {
                const int hb = (l15 >> 3) & 1;
                const int h0 = colbase / 8;
                el[n * 8 + h0 + hb] = vl0;
                er[n * 8 + h0 + hb] = vr0;
                el[n * 8 + h0 + 2 + hb] = vl1;
                er[n * 8 + h0 + 2 + hb] = vr1;
            }
        }
    }
}

// One wave per dst node, single-pass segment softmax (logits bounded; ratio exact).
__global__ void __launch_bounds__(256) aggregate_kernel(
        const float* __restrict__ feat, const float* __restrict__ el, const float* __restrict__ er,
        const int* __restrict__ csr_src, const int* __restrict__ offs,
        const float* __restrict__ bias, float* __restrict__ out, int N, int apply_act) {
    const int lane = threadIdx.x & 63;
    int node = (blockIdx.x << 2) + (threadIdx.x >> 6);
    if (node >= N) return;
    node = __builtin_amdgcn_readfirstlane(node);
    const int h = lane >> 3;
    const int beg = offs[node];
    const int end = offs[node + 1];
    const float er_n = er[node * 8 + h];

    float s = 0.f, acc = 0.f;
    int k = beg;
    for (; k + 4 <= end; k += 4) {
        int s0 = csr_src[k], s1 = csr_src[k + 1], s2 = csr_src[k + 2], s3 = csr_src[k + 3];
        float f0 = feat[(size_t)s0 * 64 + lane];
        float f1 = feat[(size_t)s1 * 64 + lane];
        float f2 = feat[(size_t)s2 * 64 + lane];
        float f3 = feat[(size_t)s3 * 64 + lane];
        float e0 = el[s0 * 8 + h] + er_n;
        float e1 = el[s1 * 8 + h] + er_n;
        float e2 = el[s2 * 8 + h] + er_n;
        float e3 = el[s3 * 8 + h] + er_n;
        e0 = (e0 >= 0.f) ? e0 : ATTN_SLOPE * e0;
        e1 = (e1 >= 0.f) ? e1 : ATTN_SLOPE * e1;
        e2 = (e2 >= 0.f) ? e2 : ATTN_SLOPE * e2;
        e3 = (e3 >= 0.f) ? e3 : ATTN_SLOPE * e3;
        float p0 = __expf(e0), p1 = __expf(e1), p2 = __expf(e2), p3 = __expf(e3);
        s += (p0 + p1) + (p2 + p3);
        acc = fmaf(p0, f0, acc);
        acc = fmaf(p1, f1, acc);
        acc = fmaf(p2, f2, acc);
        acc = fmaf(p3, f3, acc);
    }
    for (; k < end; ++k) {
        int s0 = csr_src[k];
        float f0 = feat[(size_t)s0 * 64 + lane];
        float e0 = el[s0 * 8 + h] + er_n;
        e0 = (e0 >= 0.f) ? e0 : ATTN_SLOPE * e0;
        float p0 = __expf(e0);
        s += p0;
        acc = fmaf(p0, f0, acc);
    }

    float r = (s > 0.f) ? (acc / s) : 0.f;
    r += bias[lane];
    if (apply_act) r = (r >= 0.f) ? r : ACT_SLOPE * r;
    out[(size_t)node * 64 + lane] = r;
}

extern "C" void kernel_launch(void* const* d_in, const int* in_sizes, int n_in,
                              void* d_out, int out_size, void* d_ws, size_t ws_size,
                              hipStream_t stream) {
    const float* n_feat = (const float*)d_in[0];
    const int*   src    = (const int*)d_in[1];
    const int*   dst    = (const int*)d_in[2];
    const float* W0     = (const float*)d_in[3];
    const float* al0    = (const float*)d_in[4];
    const float* ar0    = (const float*)d_in[5];
    const float* b0     = (const float*)d_in[6];
    const float* W1     = (const float*)d_in[7];
    const float* al1    = (const float*)d_in[8];
    const float* ar1    = (const float*)d_in[9];
    const float* b1     = (const float*)d_in[10];
    float* out = (float*)d_out;

    char* ws = (char*)d_ws;
    size_t off = 0;
    auto alloc = [&](size_t bytes) -> void* {
        void* p = ws + off;
        off += (bytes + 255) & ~(size_t)255;
        return p;
    };
    float* featA   = (float*)alloc((size_t)NN * 64 * 4);
    float* featB   = (float*)alloc((size_t)NN * 64 * 4);
    float* el      = (float*)alloc((size_t)NN * 8 * 4);
    float* er      = (float*)alloc((size_t)NN * 8 * 4);
    int*   offs    = (int*)alloc((size_t)(NN + 1) * 4);
    int*   csr_src = (int*)alloc((size_t)NE * 4);
    int*   tmp     = (int*)alloc((size_t)NE * 4);
    int*   bcount  = (int*)alloc((size_t)NBUK * 4);      // zeroed together with btail
    int*   btail   = (int*)alloc((size_t)NBUK * 4);
    int*   bbase   = (int*)alloc((size_t)(NBUK + 1) * 4);

    // --- build CSR by destination (bucketed, write-amplification-free) ---
    zero_ints<<<4, 256, 0, stream>>>(bcount, 2 * NBUK);  // bcount + btail contiguous
    bucket_hist<<<NBUK, 256, 0, stream>>>(dst, bcount, NE);
    scan512<<<1, NBUK, 0, stream>>>(bcount, bbase, offs);
    bucket_scatter<<<2048, 256, 0, stream>>>(src, dst, bbase, btail, tmp, NE);
    bucket_build<<<NBUK, 256, 0, stream>>>(tmp, bbase, offs, csr_src);

    const int nPairTiles = NN / 32;   // 3125 (exact)

    // --- layer 0 ---
    gemm_mfma_kernel<128><<<1024, 256, 0, stream>>>(n_feat, W0, al0, ar0, featA, el, er, nPairTiles);
    aggregate_kernel<<<(NN + 3) / 4, 256, 0, stream>>>(featA, el, er, csr_src, offs, b0, featB, NN, 1);

    // --- layer 1 ---
    gemm_mfma_kernel<64><<<1024, 256, 0, stream>>>(featB, W1, al1, ar1, featA, el, er, nPairTiles);
    aggregate_kernel<<<(NN + 3) / 4, 256, 0, stream>>>(featA, el, er, csr_src, offs, b1, out, NN, 0);
}

// Round 6
// 241.541 us; speedup vs baseline: 2.9353x; 2.9353x over previous
//
#include <hip/hip_runtime.h>
#include <math.h>

#define NN 100000
#define NE 1600000
#define ATTN_SLOPE 0.2f
#define ACT_SLOPE 0.01f

#define NBUK 512
#define BK 196            // 512*196 = 100352 >= NN; dst/BK <= 510 (<256 after -b*BK)
#define NBLK 256
#define CHUNK ((NE + NBLK - 1) / NBLK)   // 6250
#define CAP 5120          // LDS staging capacity per bucket (mean 3125, ~35 sd tail)

typedef __attribute__((ext_vector_type(8))) short bf16x8;
typedef __attribute__((ext_vector_type(4))) float f32x4;

// ---- phase 1: per-(block,bucket) histogram, LDS-aggregated, no global atomics ----
__global__ void __launch_bounds__(256) count_kernel(const int* __restrict__ dst,
                                                    int* __restrict__ counts) {
    __shared__ int h[NBUK];
    const int blk = blockIdx.x;
    for (int i = threadIdx.x; i < NBUK; i += 256) h[i] = 0;
    __syncthreads();
    const int beg = blk * CHUNK;
    const int end = (beg + CHUNK < NE) ? beg + CHUNK : NE;
    for (int i = beg + threadIdx.x; i < end; i += 256)
        atomicAdd(&h[dst[i] / BK], 1);
    __syncthreads();
    for (int i = threadIdx.x; i < NBUK; i += 256)
        counts[blk * NBUK + i] = h[i];          // coalesced row write
}

// ---- phase 2a: per-bucket exclusive scan over the 256 blocks ----
__global__ void __launch_bounds__(NBLK) scanA(const int* __restrict__ counts,
                                              int* __restrict__ wbase, int* __restrict__ btot) {
    __shared__ int lds[NBLK];
    const int b = blockIdx.x;
    const int t = threadIdx.x;
    const int v = counts[t * NBUK + b];
    lds[t] = v;
    __syncthreads();
    for (int off = 1; off < NBLK; off <<= 1) {
        int u = (t >= off) ? lds[t - off] : 0;
        __syncthreads();
        lds[t] += u;
        __syncthreads();
    }
    wbase[t * NBUK + b] = lds[t] - v;
    if (t == NBLK - 1) btot[b] = lds[t];
}

// ---- phase 2b: exclusive scan of 512 bucket totals ----
__global__ void __launch_bounds__(NBUK) scan_bucket(const int* __restrict__ btot,
                                                    int* __restrict__ bbase, int* __restrict__ offs) {
    __shared__ int lds[NBUK];
    const int t = threadIdx.x;
    const int v = btot[t];
    lds[t] = v;
    __syncthreads();
    for (int off = 1; off < NBUK; off <<= 1) {
        int u = (t >= off) ? lds[t - off] : 0;
        __syncthreads();
        lds[t] += u;
        __syncthreads();
    }
    bbase[t] = lds[t] - v;
    if (t == NBUK - 1) { bbase[NBUK] = lds[t]; offs[NN] = lds[t]; }
}

// ---- phase 3: scatter into bucket-major tmp; positions fully precomputed,
//      only LDS rank atomics; writes are ~12-element contiguous runs ----
__global__ void __launch_bounds__(256) scatter_radix(const int* __restrict__ src,
                                                     const int* __restrict__ dst,
                                                     const int* __restrict__ wbase,
                                                     const int* __restrict__ bbase,
                                                     int* __restrict__ tmp) {
    __shared__ int base[NBUK];
    __shared__ int cur[NBUK];
    const int blk = blockIdx.x;
    for (int i = threadIdx.x; i < NBUK; i += 256) {
        base[i] = bbase[i] + wbase[blk * NBUK + i];
        cur[i] = 0;
    }
    __syncthreads();
    const int beg = blk * CHUNK;
    const int end = (beg + CHUNK < NE) ? beg + CHUNK : NE;
    for (int i = beg + threadIdx.x; i < end; i += 256) {
        const int d = dst[i];
        const int b = d / BK;
        const int r = atomicAdd(&cur[b], 1);
        tmp[base[b] + r] = (src[i] << 8) | (d - b * BK);
    }
}

// ---- phase 4: one block per bucket -> local hist+scan in LDS, emit offs + csr ----
__global__ void __launch_bounds__(256) bucket_build(const int* __restrict__ tmp,
                                                    const int* __restrict__ bbase,
                                                    int* __restrict__ offs,
                                                    int* __restrict__ csr_src) {
    __shared__ int epack[CAP];
    __shared__ int csr_loc[CAP];
    __shared__ int cnt[256];
    __shared__ int loff[256];
    const int b = blockIdx.x;
    const int t = threadIdx.x;
    const int ebeg = bbase[b];
    const int nE = bbase[b + 1] - ebeg;
    const int nlo = b * BK;
    const int nn = (nlo < NN) ? ((NN - nlo < BK) ? (NN - nlo) : BK) : 0;
    const bool fits = (nE <= CAP);

    cnt[t] = 0;
    __syncthreads();
    for (int i = t; i < nE; i += 256) {
        const int p = tmp[ebeg + i];
        if (fits) epack[i] = p;
        atomicAdd(&cnt[p & 255], 1);
    }
    __syncthreads();
    const int v = cnt[t];
    for (int off = 1; off < 256; off <<= 1) {
        int u = (t >= off) ? cnt[t - off] : 0;
        __syncthreads();
        cnt[t] += u;
        __syncthreads();
    }
    const int excl = cnt[t] - v;
    loff[t] = excl;
    __syncthreads();
    cnt[t] = 0;                       // reuse as per-node tails
    if (t < nn) offs[nlo + t] = ebeg + excl;
    __syncthreads();
    for (int i = t; i < nE; i += 256) {
        const int p = fits ? epack[i] : tmp[ebeg + i];
        const int dloc = p & 255;
        const int pos = loff[dloc] + atomicAdd(&cnt[dloc], 1);
        if (fits) csr_loc[pos] = p >> 8;
        else csr_src[ebeg + pos] = p >> 8;
    }
    __syncthreads();
    if (fits)
        for (int i = t; i < nE; i += 256) csr_src[ebeg + i] = csr_loc[i];
}

// round-to-nearest-even fp32 -> bf16 bits
__device__ __forceinline__ unsigned short bfr(float f) {
    unsigned int u = __builtin_bit_cast(unsigned int, f);
    return (unsigned short)((u + 0x7fffu + ((u >> 16) & 1u)) >> 16);
}
__device__ __forceinline__ float bf2f(unsigned short h) {
    return __builtin_bit_cast(float, ((unsigned int)h) << 16);
}

// feat = x @ W via bf16x3-split MFMA (error ~2^-16, fp32-equivalent).
template <int DIN>
__global__ void __launch_bounds__(256) gemm_mfma_kernel(
        const float* __restrict__ x, const float* __restrict__ W,
        const float* __restrict__ al, const float* __restrict__ ar,
        float* __restrict__ feat, float* __restrict__ el, float* __restrict__ er,
        int nPairTiles) {
    constexpr int KS = DIN / 32;
    const int lane = threadIdx.x & 63;
    const int tw = threadIdx.x >> 6;
    const int colhalf = tw & 1;
    const int l15 = lane & 15;
    const int g = lane >> 4;
    const int colbase = colhalf * 32;

    bf16x8 Bhi[KS][2], Blo[KS][2];
#pragma unroll
    for (int ks = 0; ks < KS; ++ks) {
#pragma unroll
        for (int ct = 0; ct < 2; ++ct) {
            const int col = colbase + ct * 16 + l15;
#pragma unroll
            for (int j = 0; j < 8; ++j) {
                float w = W[(ks * 32 + g * 8 + j) * 64 + col];
                unsigned short h = bfr(w);
                Bhi[ks][ct][j] = (short)h;
                Blo[ks][ct][j] = (short)bfr(w - bf2f(h));
            }
        }
    }
    const float alc0 = al[colbase + l15];
    const float arc0 = ar[colbase + l15];
    const float alc1 = al[colbase + 16 + l15];
    const float arc1 = ar[colbase + 16 + l15];

#pragma unroll 1
    for (int pt = blockIdx.x; pt < nPairTiles; pt += gridDim.x) {
        const int rb = pt * 32 + (tw >> 1) * 16;
        f32x4 acc0 = {0.f, 0.f, 0.f, 0.f};
        f32x4 acc1 = {0.f, 0.f, 0.f, 0.f};
#pragma unroll
        for (int ks = 0; ks < KS; ++ks) {
            const float* xp = x + (size_t)(rb + l15) * DIN + ks * 32 + g * 8;
            f32x4 xa = *(const f32x4*)xp;
            f32x4 xb = *(const f32x4*)(xp + 4);
            bf16x8 Ahi, Alo;
#pragma unroll
            for (int j = 0; j < 4; ++j) {
                unsigned short h = bfr(xa[j]);
                Ahi[j] = (short)h;
                Alo[j] = (short)bfr(xa[j] - bf2f(h));
            }
#pragma unroll
            for (int j = 0; j < 4; ++j) {
                unsigned short h = bfr(xb[j]);
                Ahi[4 + j] = (short)h;
                Alo[4 + j] = (short)bfr(xb[j] - bf2f(h));
            }
            acc0 = __builtin_amdgcn_mfma_f32_16x16x32_bf16(Ahi, Bhi[ks][0], acc0, 0, 0, 0);
            acc0 = __builtin_amdgcn_mfma_f32_16x16x32_bf16(Ahi, Blo[ks][0], acc0, 0, 0, 0);
            acc0 = __builtin_amdgcn_mfma_f32_16x16x32_bf16(Alo, Bhi[ks][0], acc0, 0, 0, 0);
            acc1 = __builtin_amdgcn_mfma_f32_16x16x32_bf16(Ahi, Bhi[ks][1], acc1, 0, 0, 0);
            acc1 = __builtin_amdgcn_mfma_f32_16x16x32_bf16(Ahi, Blo[ks][1], acc1, 0, 0, 0);
            acc1 = __builtin_amdgcn_mfma_f32_16x16x32_bf16(Alo, Bhi[ks][1], acc1, 0, 0, 0);
        }
#pragma unroll
        for (int i = 0; i < 4; ++i) {
            const int n = rb + g * 4 + i;
            feat[(size_t)n * 64 + colbase + l15] = acc0[i];
            feat[(size_t)n * 64 + colbase + 16 + l15] = acc1[i];
            float vl0 = acc0[i] * alc0, vr0 = acc0[i] * arc0;
            float vl1 = acc1[i] * alc1, vr1 = acc1[i] * arc1;
#pragma unroll
            for (int d = 1; d < 8; d <<= 1) {
                vl0 += __shfl_xor(vl0, d); vr0 += __shfl_xor(vr0, d);
                vl1 += __shfl_xor(vl1, d); vr1 += __shfl_xor(vr1, d);
            }
            if ((lane & 7) == 0) {
                const int hb = (l15 >> 3) & 1;
                const int h0 = colbase / 8;
                el[n * 8 + h0 + hb] = vl0;
                er[n * 8 + h0 + hb] = vr0;
                el[n * 8 + h0 + 2 + hb] = vl1;
                er[n * 8 + h0 + 2 + hb] = vr1;
            }
        }
    }
}

// One wave per dst node, single-pass segment softmax (logits bounded; ratio exact).
__global__ void __launch_bounds__(256) aggregate_kernel(
        const float* __restrict__ feat, const float* __restrict__ el, const float* __restrict__ er,
        const int* __restrict__ csr_src, const int* __restrict__ offs,
        const float* __restrict__ bias, float* __restrict__ out, int N, int apply_act) {
    const int lane = threadIdx.x & 63;
    int node = (blockIdx.x << 2) + (threadIdx.x >> 6);
    if (node >= N) return;
    node = __builtin_amdgcn_readfirstlane(node);
    const int h = lane >> 3;
    const int beg = offs[node];
    const int end = offs[node + 1];
    const float er_n = er[node * 8 + h];

    float s = 0.f, acc = 0.f;
    int k = beg;
    for (; k + 4 <= end; k += 4) {
        int s0 = csr_src[k], s1 = csr_src[k + 1], s2 = csr_src[k + 2], s3 = csr_src[k + 3];
        float f0 = feat[(size_t)s0 * 64 + lane];
        float f1 = feat[(size_t)s1 * 64 + lane];
        float f2 = feat[(size_t)s2 * 64 + lane];
        float f3 = feat[(size_t)s3 * 64 + lane];
        float e0 = el[s0 * 8 + h] + er_n;
        float e1 = el[s1 * 8 + h] + er_n;
        float e2 = el[s2 * 8 + h] + er_n;
        float e3 = el[s3 * 8 + h] + er_n;
        e0 = (e0 >= 0.f) ? e0 : ATTN_SLOPE * e0;
        e1 = (e1 >= 0.f) ? e1 : ATTN_SLOPE * e1;
        e2 = (e2 >= 0.f) ? e2 : ATTN_SLOPE * e2;
        e3 = (e3 >= 0.f) ? e3 : ATTN_SLOPE * e3;
        float p0 = __expf(e0), p1 = __expf(e1), p2 = __expf(e2), p3 = __expf(e3);
        s += (p0 + p1) + (p2 + p3);
        acc = fmaf(p0, f0, acc);
        acc = fmaf(p1, f1, acc);
        acc = fmaf(p2, f2, acc);
        acc = fmaf(p3, f3, acc);
    }
    for (; k < end; ++k) {
        int s0 = csr_src[k];
        float f0 = feat[(size_t)s0 * 64 + lane];
        float e0 = el[s0 * 8 + h] + er_n;
        e0 = (e0 >= 0.f) ? e0 : ATTN_SLOPE * e0;
        float p0 = __expf(e0);
        s += p0;
        acc = fmaf(p0, f0, acc);
    }

    float r = (s > 0.f) ? (acc / s) : 0.f;
    r += bias[lane];
    if (apply_act) r = (r >= 0.f) ? r : ACT_SLOPE * r;
    out[(size_t)node * 64 + lane] = r;
}

extern "C" void kernel_launch(void* const* d_in, const int* in_sizes, int n_in,
                              void* d_out, int out_size, void* d_ws, size_t ws_size,
                              hipStream_t stream) {
    const float* n_feat = (const float*)d_in[0];
    const int*   src    = (const int*)d_in[1];
    const int*   dst    = (const int*)d_in[2];
    const float* W0     = (const float*)d_in[3];
    const float* al0    = (const float*)d_in[4];
    const float* ar0    = (const float*)d_in[5];
    const float* b0     = (const float*)d_in[6];
    const float* W1     = (const float*)d_in[7];
    const float* al1    = (const float*)d_in[8];
    const float* ar1    = (const float*)d_in[9];
    const float* b1     = (const float*)d_in[10];
    float* out = (float*)d_out;

    char* ws = (char*)d_ws;
    size_t off = 0;
    auto alloc = [&](size_t bytes) -> void* {
        void* p = ws + off;
        off += (bytes + 255) & ~(size_t)255;
        return p;
    };
    float* featA   = (float*)alloc((size_t)NN * 64 * 4);
    float* featB   = (float*)alloc((size_t)NN * 64 * 4);
    float* el      = (float*)alloc((size_t)NN * 8 * 4);
    float* er      = (float*)alloc((size_t)NN * 8 * 4);
    int*   offs    = (int*)alloc((size_t)(NN + 1) * 4);
    int*   csr_src = (int*)alloc((size_t)NE * 4);
    int*   tmp     = (int*)alloc((size_t)NE * 4);
    int*   counts  = (int*)alloc((size_t)NBLK * NBUK * 4);
    int*   wbase   = (int*)alloc((size_t)NBLK * NBUK * 4);
    int*   btot    = (int*)alloc((size_t)NBUK * 4);
    int*   bbase   = (int*)alloc((size_t)(NBUK + 1) * 4);

    // --- build CSR by destination (radix-partition, zero global atomics) ---
    count_kernel<<<NBLK, 256, 0, stream>>>(dst, counts);
    scanA<<<NBUK, NBLK, 0, stream>>>(counts, wbase, btot);
    scan_bucket<<<1, NBUK, 0, stream>>>(btot, bbase, offs);
    scatter_radix<<<NBLK, 256, 0, stream>>>(src, dst, wbase, bbase, tmp);
    bucket_build<<<NBUK, 256, 0, stream>>>(tmp, bbase, offs, csr_src);

    const int nPairTiles = NN / 32;   // 3125 (exact)

    // --- layer 0 ---
    gemm_mfma_kernel<128><<<1024, 256, 0, stream>>>(n_feat, W0, al0, ar0, featA, el, er, nPairTiles);
    aggregate_kernel<<<(NN + 3) / 4, 256, 0, stream>>>(featA, el, er, csr_src, offs, b0, featB, NN, 1);

    // --- layer 1 ---
    gemm_mfma_kernel<64><<<1024, 256, 0, stream>>>(featB, W1, al1, ar1, featA, el, er, nPairTiles);
    aggregate_kernel<<<(NN + 3) / 4, 256, 0, stream>>>(featA, el, er, csr_src, offs, b1, out, NN, 0);
}

// Round 7
// 195.840 us; speedup vs baseline: 3.6202x; 1.2334x over previous
//
#include <hip/hip_runtime.h>
#include <math.h>

#define NN 100000
#define NE 1600000
#define ATTN_SLOPE 0.2f
#define ACT_SLOPE 0.01f

#define NBUK 512
#define BK 196            // 512*196 = 100352 >= NN; dst/BK <= 510 (<256 after -b*BK)
#define NBLK 256
#define CHUNK ((NE + NBLK - 1) / NBLK)   // 6250
#define CAP 5120          // LDS staging capacity per bucket (mean 3125, ~35 sd tail)

typedef __attribute__((ext_vector_type(8))) short bf16x8;
typedef __attribute__((ext_vector_type(4))) float f32x4;

// ---- phase 1: per-(block,bucket) histogram, LDS-aggregated, no global atomics ----
__global__ void __launch_bounds__(256) count_kernel(const int* __restrict__ dst,
                                                    int* __restrict__ counts) {
    __shared__ int h[NBUK];
    const int blk = blockIdx.x;
    for (int i = threadIdx.x; i < NBUK; i += 256) h[i] = 0;
    __syncthreads();
    const int beg = blk * CHUNK;
    const int end = (beg + CHUNK < NE) ? beg + CHUNK : NE;
    for (int i = beg + threadIdx.x; i < end; i += 256)
        atomicAdd(&h[dst[i] / BK], 1);
    __syncthreads();
    for (int i = threadIdx.x; i < NBUK; i += 256)
        counts[blk * NBUK + i] = h[i];          // coalesced row write
}

// ---- phase 2a: per-bucket exclusive scan over the 256 blocks ----
__global__ void __launch_bounds__(NBLK) scanA(const int* __restrict__ counts,
                                              int* __restrict__ wbase, int* __restrict__ btot) {
    __shared__ int lds[NBLK];
    const int b = blockIdx.x;
    const int t = threadIdx.x;
    const int v = counts[t * NBUK + b];
    lds[t] = v;
    __syncthreads();
    for (int off = 1; off < NBLK; off <<= 1) {
        int u = (t >= off) ? lds[t - off] : 0;
        __syncthreads();
        lds[t] += u;
        __syncthreads();
    }
    wbase[t * NBUK + b] = lds[t] - v;
    if (t == NBLK - 1) btot[b] = lds[t];
}

// ---- phase 2b: exclusive scan of 512 bucket totals ----
__global__ void __launch_bounds__(NBUK) scan_bucket(const int* __restrict__ btot,
                                                    int* __restrict__ bbase, int* __restrict__ offs) {
    __shared__ int lds[NBUK];
    const int t = threadIdx.x;
    const int v = btot[t];
    lds[t] = v;
    __syncthreads();
    for (int off = 1; off < NBUK; off <<= 1) {
        int u = (t >= off) ? lds[t - off] : 0;
        __syncthreads();
        lds[t] += u;
        __syncthreads();
    }
    bbase[t] = lds[t] - v;
    if (t == NBUK - 1) { bbase[NBUK] = lds[t]; offs[NN] = lds[t]; }
}

// ---- phase 3: scatter into bucket-major tmp; positions fully precomputed,
//      only LDS rank atomics; writes are ~12-element contiguous runs ----
__global__ void __launch_bounds__(256) scatter_radix(const int* __restrict__ src,
                                                     const int* __restrict__ dst,
                                                     const int* __restrict__ wbase,
                                                     const int* __restrict__ bbase,
                                                     int* __restrict__ tmp) {
    __shared__ int base[NBUK];
    __shared__ int cur[NBUK];
    const int blk = blockIdx.x;
    for (int i = threadIdx.x; i < NBUK; i += 256) {
        base[i] = bbase[i] + wbase[blk * NBUK + i];
        cur[i] = 0;
    }
    __syncthreads();
    const int beg = blk * CHUNK;
    const int end = (beg + CHUNK < NE) ? beg + CHUNK : NE;
    for (int i = beg + threadIdx.x; i < end; i += 256) {
        const int d = dst[i];
        const int b = d / BK;
        const int r = atomicAdd(&cur[b], 1);
        tmp[base[b] + r] = (src[i] << 8) | (d - b * BK);
    }
}

// ---- phase 4: one block per bucket -> local hist+scan in LDS, emit offs + csr ----
__global__ void __launch_bounds__(256) bucket_build(const int* __restrict__ tmp,
                                                    const int* __restrict__ bbase,
                                                    int* __restrict__ offs,
                                                    int* __restrict__ csr_src) {
    __shared__ int epack[CAP];
    __shared__ int csr_loc[CAP];
    __shared__ int cnt[256];
    __shared__ int loff[256];
    const int b = blockIdx.x;
    const int t = threadIdx.x;
    const int ebeg = bbase[b];
    const int nE = bbase[b + 1] - ebeg;
    const int nlo = b * BK;
    const int nn = (nlo < NN) ? ((NN - nlo < BK) ? (NN - nlo) : BK) : 0;
    const bool fits = (nE <= CAP);

    cnt[t] = 0;
    __syncthreads();
    for (int i = t; i < nE; i += 256) {
        const int p = tmp[ebeg + i];
        if (fits) epack[i] = p;
        atomicAdd(&cnt[p & 255], 1);
    }
    __syncthreads();
    const int v = cnt[t];
    for (int off = 1; off < 256; off <<= 1) {
        int u = (t >= off) ? cnt[t - off] : 0;
        __syncthreads();
        cnt[t] += u;
        __syncthreads();
    }
    const int excl = cnt[t] - v;
    loff[t] = excl;
    __syncthreads();
    cnt[t] = 0;                       // reuse as per-node tails
    if (t < nn) offs[nlo + t] = ebeg + excl;
    __syncthreads();
    for (int i = t; i < nE; i += 256) {
        const int p = fits ? epack[i] : tmp[ebeg + i];
        const int dloc = p & 255;
        const int pos = loff[dloc] + atomicAdd(&cnt[dloc], 1);
        if (fits) csr_loc[pos] = p >> 8;
        else csr_src[ebeg + pos] = p >> 8;
    }
    __syncthreads();
    if (fits)
        for (int i = t; i < nE; i += 256) csr_src[ebeg + i] = csr_loc[i];
}

// round-to-nearest-even fp32 -> bf16 bits
__device__ __forceinline__ unsigned short bfr(float f) {
    unsigned int u = __builtin_bit_cast(unsigned int, f);
    return (unsigned short)((u + 0x7fffu + ((u >> 16) & 1u)) >> 16);
}
__device__ __forceinline__ float bf2f(unsigned short h) {
    return __builtin_bit_cast(float, ((unsigned int)h) << 16);
}

// feat = x @ W via bf16x3-split MFMA (error ~2^-16, fp32-equivalent).
// feat is stored as bf16 (sole consumer is aggregate's alpha-weighted sum).
template <int DIN>
__global__ void __launch_bounds__(256) gemm_mfma_kernel(
        const float* __restrict__ x, const float* __restrict__ W,
        const float* __restrict__ al, const float* __restrict__ ar,
        unsigned short* __restrict__ feat, float* __restrict__ el, float* __restrict__ er,
        int nPairTiles) {
    constexpr int KS = DIN / 32;
    const int lane = threadIdx.x & 63;
    const int tw = threadIdx.x >> 6;
    const int colhalf = tw & 1;
    const int l15 = lane & 15;
    const int g = lane >> 4;
    const int colbase = colhalf * 32;

    bf16x8 Bhi[KS][2], Blo[KS][2];
#pragma unroll
    for (int ks = 0; ks < KS; ++ks) {
#pragma unroll
        for (int ct = 0; ct < 2; ++ct) {
            const int col = colbase + ct * 16 + l15;
#pragma unroll
            for (int j = 0; j < 8; ++j) {
                float w = W[(ks * 32 + g * 8 + j) * 64 + col];
                unsigned short h = bfr(w);
                Bhi[ks][ct][j] = (short)h;
                Blo[ks][ct][j] = (short)bfr(w - bf2f(h));
            }
        }
    }
    const float alc0 = al[colbase + l15];
    const float arc0 = ar[colbase + l15];
    const float alc1 = al[colbase + 16 + l15];
    const float arc1 = ar[colbase + 16 + l15];

#pragma unroll 1
    for (int pt = blockIdx.x; pt < nPairTiles; pt += gridDim.x) {
        const int rb = pt * 32 + (tw >> 1) * 16;
        f32x4 acc0 = {0.f, 0.f, 0.f, 0.f};
        f32x4 acc1 = {0.f, 0.f, 0.f, 0.f};
#pragma unroll
        for (int ks = 0; ks < KS; ++ks) {
            const float* xp = x + (size_t)(rb + l15) * DIN + ks * 32 + g * 8;
            f32x4 xa = *(const f32x4*)xp;
            f32x4 xb = *(const f32x4*)(xp + 4);
            bf16x8 Ahi, Alo;
#pragma unroll
            for (int j = 0; j < 4; ++j) {
                unsigned short h = bfr(xa[j]);
                Ahi[j] = (short)h;
                Alo[j] = (short)bfr(xa[j] - bf2f(h));
            }
#pragma unroll
            for (int j = 0; j < 4; ++j) {
                unsigned short h = bfr(xb[j]);
                Ahi[4 + j] = (short)h;
                Alo[4 + j] = (short)bfr(xb[j] - bf2f(h));
            }
            acc0 = __builtin_amdgcn_mfma_f32_16x16x32_bf16(Ahi, Bhi[ks][0], acc0, 0, 0, 0);
            acc0 = __builtin_amdgcn_mfma_f32_16x16x32_bf16(Ahi, Blo[ks][0], acc0, 0, 0, 0);
            acc0 = __builtin_amdgcn_mfma_f32_16x16x32_bf16(Alo, Bhi[ks][0], acc0, 0, 0, 0);
            acc1 = __builtin_amdgcn_mfma_f32_16x16x32_bf16(Ahi, Bhi[ks][1], acc1, 0, 0, 0);
            acc1 = __builtin_amdgcn_mfma_f32_16x16x32_bf16(Ahi, Blo[ks][1], acc1, 0, 0, 0);
            acc1 = __builtin_amdgcn_mfma_f32_16x16x32_bf16(Alo, Bhi[ks][1], acc1, 0, 0, 0);
        }
#pragma unroll
        for (int i = 0; i < 4; ++i) {
            const int n = rb + g * 4 + i;
            feat[(size_t)n * 64 + colbase + l15] = bfr(acc0[i]);
            feat[(size_t)n * 64 + colbase + 16 + l15] = bfr(acc1[i]);
            float vl0 = acc0[i] * alc0, vr0 = acc0[i] * arc0;
            float vl1 = acc1[i] * alc1, vr1 = acc1[i] * arc1;
#pragma unroll
            for (int d = 1; d < 8; d <<= 1) {
                vl0 += __shfl_xor(vl0, d); vr0 += __shfl_xor(vr0, d);
                vl1 += __shfl_xor(vl1, d); vr1 += __shfl_xor(vr1, d);
            }
            if ((lane & 7) == 0) {
                const int hb = (l15 >> 3) & 1;
                const int h0 = colbase / 8;
                el[n * 8 + h0 + hb] = vl0;
                er[n * 8 + h0 + hb] = vr0;
                el[n * 8 + h0 + 2 + hb] = vl1;
                er[n * 8 + h0 + 2 + hb] = vr1;
            }
        }
    }
}

// One wave per dst node, single-pass segment softmax (logits bounded; ratio exact).
// feat gathered as bf16 (128 B/row); unroll 8 -> 8 gathers in flight per wave.
__global__ void __launch_bounds__(256) aggregate_kernel(
        const unsigned short* __restrict__ feat, const float* __restrict__ el,
        const float* __restrict__ er,
        const int* __restrict__ csr_src, const int* __restrict__ offs,
        const float* __restrict__ bias, float* __restrict__ out, int N, int apply_act) {
    const int lane = threadIdx.x & 63;
    int node = (blockIdx.x << 2) + (threadIdx.x >> 6);
    if (node >= N) return;
    node = __builtin_amdgcn_readfirstlane(node);
    const int h = lane >> 3;
    const int beg = offs[node];
    const int end = offs[node + 1];
    const float er_n = er[node * 8 + h];

    float s0a = 0.f, s1a = 0.f, a0a = 0.f, a1a = 0.f;
    int k = beg;
    for (; k + 8 <= end; k += 8) {
        int si[8];
        unsigned short fu[8];
        float ev[8];
#pragma unroll
        for (int j = 0; j < 8; ++j) si[j] = csr_src[k + j];
#pragma unroll
        for (int j = 0; j < 8; ++j) fu[j] = feat[(size_t)si[j] * 64 + lane];
#pragma unroll
        for (int j = 0; j < 8; ++j) ev[j] = el[si[j] * 8 + h] + er_n;
#pragma unroll
        for (int j = 0; j < 8; ++j) {
            float e = ev[j];
            e = (e >= 0.f) ? e : ATTN_SLOPE * e;
            float p = __expf(e);
            if (j & 1) { s1a += p; a1a = fmaf(p, bf2f(fu[j]), a1a); }
            else       { s0a += p; a0a = fmaf(p, bf2f(fu[j]), a0a); }
        }
    }
    for (; k + 4 <= end; k += 4) {
        int si[4];
        unsigned short fu[4];
        float ev[4];
#pragma unroll
        for (int j = 0; j < 4; ++j) si[j] = csr_src[k + j];
#pragma unroll
        for (int j = 0; j < 4; ++j) fu[j] = feat[(size_t)si[j] * 64 + lane];
#pragma unroll
        for (int j = 0; j < 4; ++j) ev[j] = el[si[j] * 8 + h] + er_n;
#pragma unroll
        for (int j = 0; j < 4; ++j) {
            float e = ev[j];
            e = (e >= 0.f) ? e : ATTN_SLOPE * e;
            float p = __expf(e);
            if (j & 1) { s1a += p; a1a = fmaf(p, bf2f(fu[j]), a1a); }
            else       { s0a += p; a0a = fmaf(p, bf2f(fu[j]), a0a); }
        }
    }
    for (; k < end; ++k) {
        int sn = csr_src[k];
        unsigned short fv = feat[(size_t)sn * 64 + lane];
        float e = el[sn * 8 + h] + er_n;
        e = (e >= 0.f) ? e : ATTN_SLOPE * e;
        float p = __expf(e);
        s0a += p;
        a0a = fmaf(p, bf2f(fv), a0a);
    }

    const float s = s0a + s1a;
    const float acc = a0a + a1a;
    float r = (s > 0.f) ? (acc / s) : 0.f;
    r += bias[lane];
    if (apply_act) r = (r >= 0.f) ? r : ACT_SLOPE * r;
    out[(size_t)node * 64 + lane] = r;
}

extern "C" void kernel_launch(void* const* d_in, const int* in_sizes, int n_in,
                              void* d_out, int out_size, void* d_ws, size_t ws_size,
                              hipStream_t stream) {
    const float* n_feat = (const float*)d_in[0];
    const int*   src    = (const int*)d_in[1];
    const int*   dst    = (const int*)d_in[2];
    const float* W0     = (const float*)d_in[3];
    const float* al0    = (const float*)d_in[4];
    const float* ar0    = (const float*)d_in[5];
    const float* b0     = (const float*)d_in[6];
    const float* W1     = (const float*)d_in[7];
    const float* al1    = (const float*)d_in[8];
    const float* ar1    = (const float*)d_in[9];
    const float* b1     = (const float*)d_in[10];
    float* out = (float*)d_out;

    char* ws = (char*)d_ws;
    size_t off = 0;
    auto alloc = [&](size_t bytes) -> void* {
        void* p = ws + off;
        off += (bytes + 255) & ~(size_t)255;
        return p;
    };
    unsigned short* featA = (unsigned short*)alloc((size_t)NN * 64 * 2);
    float* featB   = (float*)alloc((size_t)NN * 64 * 4);   // layer-1 h (fp32, feeds GEMM<64>)
    float* el      = (float*)alloc((size_t)NN * 8 * 4);
    float* er      = (float*)alloc((size_t)NN * 8 * 4);
    int*   offs    = (int*)alloc((size_t)(NN + 1) * 4);
    int*   csr_src = (int*)alloc((size_t)NE * 4);
    int*   tmp     = (int*)alloc((size_t)NE * 4);
    int*   counts  = (int*)alloc((size_t)NBLK * NBUK * 4);
    int*   wbase   = (int*)alloc((size_t)NBLK * NBUK * 4);
    int*   btot    = (int*)alloc((size_t)NBUK * 4);
    int*   bbase   = (int*)alloc((size_t)(NBUK + 1) * 4);

    // --- build CSR by destination (radix-partition, zero global atomics) ---
    count_kernel<<<NBLK, 256, 0, stream>>>(dst, counts);
    scanA<<<NBUK, NBLK, 0, stream>>>(counts, wbase, btot);
    scan_bucket<<<1, NBUK, 0, stream>>>(btot, bbase, offs);
    scatter_radix<<<NBLK, 256, 0, stream>>>(src, dst, wbase, bbase, tmp);
    bucket_build<<<NBUK, 256, 0, stream>>>(tmp, bbase, offs, csr_src);

    const int nPairTiles = NN / 32;   // 3125 (exact)

    // --- layer 0 ---
    gemm_mfma_kernel<128><<<1024, 256, 0, stream>>>(n_feat, W0, al0, ar0, featA, el, er, nPairTiles);
    aggregate_kernel<<<(NN + 3) / 4, 256, 0, stream>>>(featA, el, er, csr_src, offs, b0, featB, NN, 1);

    // --- layer 1 ---
    gemm_mfma_kernel<64><<<1024, 256, 0, stream>>>(featB, W1, al1, ar1, featA, el, er, nPairTiles);
    aggregate_kernel<<<(NN + 3) / 4, 256, 0, stream>>>(featA, el, er, csr_src, offs, b1, out, NN, 0);
}